// Round 8
// baseline (639.415 us; speedup 1.0000x reference)
//
#include <hip/hip_runtime.h>

typedef _Float16 half2v __attribute__((ext_vector_type(2)));
typedef _Float16 f16x8  __attribute__((ext_vector_type(8)));
typedef float    f32x4  __attribute__((ext_vector_type(4)));

#define T_LEN 1024
#define NBATCH 1024
#define HID 20
#define G_B 4       // batch elements per BLOCK (2 chains per lane)
#define STEPS 16    // timesteps per superstep (one barrier per STEPS steps)
#define RSLOT 128   // halfs per ring timestep slot (4 batches x 32, zero-padded)
#define PPITCH 84   // pre-gate LDS row pitch in dwords (80 + 4 pad, 336B: 16B-aligned)

#if defined(__has_builtin)
#if __has_builtin(__builtin_amdgcn_fdot2)
#define HAVE_FDOT2 1
#endif
#endif

#define NLOG2E  -1.4426950408889634f   // -log2(e):  sigmoid gates
#define N2LOG2E -2.8853900817779268f   // -2log2(e): tanh gates

__device__ __forceinline__ float fdot2_(half2v a, half2v b, float c) {
#ifdef HAVE_FDOT2
    return __builtin_amdgcn_fdot2(a, b, c, false);
#else
    return c + (float)a[0] * (float)b[0] + (float)a[1] * (float)b[1];
#endif
}

__device__ __forceinline__ half2v pack2(float a, float b) {
    half2v r; r[0] = (_Float16)a; r[1] = (_Float16)b; return r;
}

// Load 20 f16 (one 32-half row, 16B-aligned) into 10 half2.
__device__ __forceinline__ void load_h20(const _Float16* row, half2v hp[10]) {
    uint4 q0 = *(const uint4*)(row);
    uint4 q1 = *(const uint4*)(row + 8);
    uint2 q2 = *(const uint2*)(row + 16);
    hp[0] = __builtin_bit_cast(half2v, q0.x);
    hp[1] = __builtin_bit_cast(half2v, q0.y);
    hp[2] = __builtin_bit_cast(half2v, q0.z);
    hp[3] = __builtin_bit_cast(half2v, q0.w);
    hp[4] = __builtin_bit_cast(half2v, q1.x);
    hp[5] = __builtin_bit_cast(half2v, q1.y);
    hp[6] = __builtin_bit_cast(half2v, q1.z);
    hp[7] = __builtin_bit_cast(half2v, q1.w);
    hp[8] = __builtin_bit_cast(half2v, q2.x);
    hp[9] = __builtin_bit_cast(half2v, q2.y);
}

// 20-element dot, two independent depth-5 chains, seeded with `seed`.
// EXACT R18 op order — do not touch (recurrence is chaos-sensitive).
__device__ __forceinline__ float dot20s(const half2v W[10], const half2v h[10],
                                        float seed) {
    float a0 = seed, a1 = 0.f;
#pragma unroll
    for (int k = 0; k < 5; ++k) {
        a0 = fdot2_(W[k],     h[k],     a0);
        a1 = fdot2_(W[k + 5], h[k + 5], a1);
    }
    return a0 + a1;
}

// EXACT R18 activation sequence (two-rcp, shared-rcp pairs).
__device__ __forceinline__ float lstm_cell(float p0, float p1, float p2,
                                           float p3, float& c) {
    const float ei = __builtin_exp2f(p0);
    const float ef = __builtin_exp2f(p1);
    const float eg = __builtin_exp2f(p2);
    const float eo = __builtin_exp2f(p3);
    const float sf = __builtin_amdgcn_rcpf(1.0f + ef);
    const float u  = (1.0f - eg) *
        __builtin_amdgcn_rcpf((1.0f + ei) * (1.0f + eg));
    c = sf * c + u;                   // sigma(f)*c + sigma(i)*tanh(g)
    const float ec = __builtin_exp2f(N2LOG2E * c);
    return (1.0f - ec) *
        __builtin_amdgcn_rcpf((1.0f + eo) * (1.0f + ec));
}

// R23: the serial region is LATENCY-dominated (R18 wall/step ~1164cy vs
// ~215cy issue; R22's bpermute detour regressed). Attack with parallelism,
// not scheduling: 2 INDEPENDENT recurrence chains per lane (ILP-2 hides
// each chain's write->read + transcendental latency with the other's
// compute) and G_B=4 -> grid 256 = exactly 1 block/CU (zero SIMD
// contention, no inter-block barrier interference).
//   lane = (pr = lane>>5, j = lane&31, act if j<20); chains = batches
//   {2pr, 2pr+1}. Per-chain math is verbatim R18 (bit-identical output;
//   absmax self-check = 0.001953125).
//   ih-MFMA: pre-row = 4*step+batch, 4 A-halves x 5 col-tiles = 20 MFMAs,
//   transposed scatter col = j*4+gt (R18's proven pattern).
//   pf reads per-step (2 x b128, prefetchable) to keep VGPR in budget.
__global__ void __launch_bounds__(192, 1) lstm3_r23(
    const float* __restrict__ x,
    const float* __restrict__ wih0, const float* __restrict__ whh0,
    const float* __restrict__ bih0, const float* __restrict__ bhh0,
    const float* __restrict__ wih1, const float* __restrict__ whh1,
    const float* __restrict__ bih1, const float* __restrict__ bhh1,
    const float* __restrict__ wih2, const float* __restrict__ whh2,
    const float* __restrict__ bih2, const float* __restrict__ bhh2,
    const float* __restrict__ fcw, const float* __restrict__ fcb,
    float* __restrict__ out)
{
    __shared__ __align__(16) float xlds[G_B * T_LEN];             // [t][b] 16KB
    __shared__ __align__(16) _Float16 rings[3][2 * STEPS][RSLOT]; // 24KB
    __shared__ __align__(16) float plds[2][4 * STEPS][PPITCH];    // 43KB

    const int tid = threadIdx.x;
    const int wv = tid / 64;
    const int lane = tid & 63;
    const long b_base = (long)blockIdx.x * G_B;

    {
        // stage x interleaved: xlds[4*t + b] = x[b_base+b][t]
        const float* xg = x + b_base * T_LEN;
        for (int i = tid; i < G_B * T_LEN; i += 192) {
            const int t = i & (T_LEN - 1);
            const int b = i >> 10;
            xlds[4 * t + b] = xg[i];
        }
        for (int i = tid; i < 3 * 2 * STEPS * RSLOT; i += 192)
            ((_Float16*)rings)[i] = (_Float16)0.0f;
    }

    const int pr = lane >> 5;            // chain-pair index: 0 or 1
    const int lj = lane & 31;
    const bool act = lj < HID;
    const int j = act ? lj : 0;
    const int b0 = 2 * pr;               // first batch of this lane
    const int b1 = 2 * pr + 1;           // second batch

    const float* whh = (wv == 0) ? whh0 : (wv == 1) ? whh1 : whh2;
    const float* wih = (wv == 0) ? wih0 : (wv == 1) ? wih1 : wih2;
    const float* bih = (wv == 0) ? bih0 : (wv == 1) ? bih1 : bih2;
    const float* bhh = (wv == 0) ? bhh0 : (wv == 1) ? bhh1 : bhh2;

    // All 4 gate rows (i,f,g,o) of unit j in VGPRs, pre-scaled by the
    // activation's log2 factor (i,f,o: -log2e; g: -2log2e). Shared by
    // both chains (same layer).
    half2v Whh[4][10];
    float bias[4];
    float wx[4] = {0.f, 0.f, 0.f, 0.f};
#pragma unroll
    for (int gt = 0; gt < 4; ++gt) {
        const float sc = (gt == 2) ? N2LOG2E : NLOG2E;
        const int r = gt * HID + j;
#pragma unroll
        for (int k4 = 0; k4 < 5; ++k4) {
            float4 v = *(const float4*)(whh + r * HID + 4 * k4);
            Whh[gt][2 * k4]     = pack2(sc * v.x, sc * v.y);
            Whh[gt][2 * k4 + 1] = pack2(sc * v.z, sc * v.w);
        }
        bias[gt] = sc * (bih[r] + bhh[r]);
        if (wv == 0) wx[gt] = sc * wih[r];  // w_ih0 is (80,1)
    }

    // B fragments for the ih MFMA (waves 1,2): lane holds 8 contiguous k of
    // W_ih row n = t*16 + (lane&15), k-chunk = (lane>>4)*8, zero-padded k>=20.
    f16x8 WihB[5];
    int col4[5];  // transposed scatter column: (n%20)*4 + n/20
    if (wv > 0) {
        const int kc = (lane >> 4) * 8;
        const int col = lane & 15;
#pragma unroll
        for (int t = 0; t < 5; ++t) {
            const int n = t * 16 + col;           // 0..79
            const int gt = n / HID;               // gate of this column
            const float sc = (gt == 2) ? N2LOG2E : NLOG2E;
            f16x8 v;
#pragma unroll
            for (int e = 0; e < 8; ++e) {
                const int k = kc + e;
                const float w = (k < HID) ? wih[n * HID + k] : 0.f;
                v[e] = (_Float16)(sc * w);
            }
            WihB[t] = v;
            col4[t] = (n % HID) * 4 + gt;
        }
    }

    _Float16* const own_base = &rings[wv][0][0];
    const _Float16* const bel_base = (wv > 0) ? &rings[wv - 1][0][0]
                                              : &rings[0][0][0];
    float* const myp = &plds[(wv > 0) ? (wv - 1) : 0][0][0];
    // consumer pre-read bases: row (4i+b), col 4j (b128, 16B aligned)
    const float* const prb0 = myp + b0 * PPITCH + 4 * j;
    const float* const prb1 = myp + b1 * PPITCH + 4 * j;

    float c0 = 0.0f, c1 = 0.0f;          // cell states (2 chains)
    // carried own-h partials: oA = bias + Whh.h(t-1); h(-1)=0 -> bias
    float oA0[4] = {bias[0], bias[1], bias[2], bias[3]};
    float oA1[4] = {bias[0], bias[1], bias[2], bias[3]};

    __syncthreads();

    const int SS = T_LEN / STEPS;  // supersteps per wave (64)

    for (int s = 0; s < SS + 2; ++s) {
        const int m = s - wv;
        if (m >= 0 && m < SS) {
            const int t0 = STEPS * m;
            const int hb = (m & 1) * (STEPS * RSLOT);  // ring half (halfs)

            float xr0[STEPS], xr1[STEPS];   // wave 0: hoisted x (2 chains)

            if (wv > 0) {
                // ---- ih pre-gates: 16 steps x 4 batches = 20 MFMAs ----
                // A-half h covers pre-rows 16h..16h+15; pre-row = 4*step+batch
                // -> A row ar: step = 4h + (ar>>2), batch = ar&3.
                const int ar = lane & 15;
                const int kc = (lane >> 4) * 8;
                const int crow = (lane >> 4) * 4;
                const f32x4 z = {0.f, 0.f, 0.f, 0.f};
#pragma unroll
                for (int h = 0; h < 4; ++h) {
                    const _Float16* ab = bel_base + hb
                        + (4 * h + (ar >> 2)) * RSLOT + (ar & 3) * 32 + kc;
                    const f16x8 af = *(const f16x8*)ab;
#pragma unroll
                    for (int t = 0; t < 5; ++t) {
                        f32x4 acc = __builtin_amdgcn_mfma_f32_16x16x32_f16(
                            af, WihB[t], z, 0, 0, 0);
                        float* wrow = myp + (crow + 16 * h) * PPITCH + col4[t];
#pragma unroll
                        for (int q = 0; q < 4; ++q)
                            wrow[q * PPITCH] = acc[q];
                    }
                }
            } else {
                const float* xp = xlds + 4 * t0;
#pragma unroll
                for (int i = 0; i < STEPS; ++i) {
                    xr0[i] = xp[4 * i + b0];
                    xr1[i] = xp[4 * i + b1];
                }
            }

            // ---- serial chain: 16 steps x 2 independent chains (ILP-2) ----
            const int qo0 = hb + b0 * 32;
            const int qo1 = hb + b1 * 32;
#pragma unroll
            for (int i = 0; i < STEPS; ++i) {
                float p0[4], p1[4];
                if (wv == 0) {
#pragma unroll
                    for (int gt = 0; gt < 4; ++gt) {
                        p0[gt] = oA0[gt] + wx[gt] * xr0[i];
                        p1[gt] = oA1[gt] + wx[gt] * xr1[i];
                    }
                } else {
                    const f32x4 pf0 = *(const f32x4*)(prb0 + 4 * i * PPITCH);
                    const f32x4 pf1 = *(const f32x4*)(prb1 + 4 * i * PPITCH);
#pragma unroll
                    for (int gt = 0; gt < 4; ++gt) {
                        p0[gt] = oA0[gt] + pf0[gt];
                        p1[gt] = oA1[gt] + pf1[gt];
                    }
                }
                const float hn0 = lstm_cell(p0[0], p0[1], p0[2], p0[3], c0);
                const float hn1 = lstm_cell(p1[0], p1[1], p1[2], p1[3], c1);

                const _Float16 hf0 = (_Float16)hn0;
                const _Float16 hf1 = (_Float16)hn1;
                _Float16* const sp = own_base + i * RSLOT;
                if (act) sp[qo0 + j] = hf0;
                if (act) sp[qo1 + j] = hf1;
                // own-h readback + dots (same-wave in-order DS, no sync);
                // the two chains' round trips overlap each other (ILP-2)
                half2v ho0[10], ho1[10];
                load_h20(sp + qo0, ho0);
                load_h20(sp + qo1, ho1);
#pragma unroll
                for (int gt = 0; gt < 4; ++gt)
                    oA0[gt] = dot20s(Whh[gt], ho0, bias[gt]);
#pragma unroll
                for (int gt = 0; gt < 4; ++gt)
                    oA1[gt] = dot20s(Whh[gt], ho1, bias[gt]);
            }
        }
        __syncthreads();  // publish this superstep's 16 rows to the wave above
    }

    // FC epilogue: h2(T-1): m=63 (odd half), i=15 -> ring slot 31
    if (wv == 2 && lane < 2 * G_B) {
        const int gg = lane >> 1, o = lane & 1;
        float acc = fcb[o];
        const _Float16* h2 = &rings[2][2 * STEPS - 1][gg * 32];
#pragma unroll
        for (int k = 0; k < HID; ++k) {
            acc += fcw[o * HID + k] * (float)h2[k];
        }
        out[(b_base + gg) * 2 + o] = acc;
    }
}

extern "C" void kernel_launch(void* const* d_in, const int* in_sizes, int n_in,
                              void* d_out, int out_size, void* d_ws, size_t ws_size,
                              hipStream_t stream) {
    const float* x    = (const float*)d_in[0];
    const float* wih0 = (const float*)d_in[1];
    const float* whh0 = (const float*)d_in[2];
    const float* bih0 = (const float*)d_in[3];
    const float* bhh0 = (const float*)d_in[4];
    const float* wih1 = (const float*)d_in[5];
    const float* whh1 = (const float*)d_in[6];
    const float* bih1 = (const float*)d_in[7];
    const float* bhh1 = (const float*)d_in[8];
    const float* wih2 = (const float*)d_in[9];
    const float* whh2 = (const float*)d_in[10];
    const float* bih2 = (const float*)d_in[11];
    const float* bhh2 = (const float*)d_in[12];
    const float* fcw  = (const float*)d_in[13];
    const float* fcb  = (const float*)d_in[14];

    lstm3_r23<<<dim3(NBATCH / G_B), dim3(192), 0, stream>>>(
        x, wih0, whh0, bih0, bhh0,
        wih1, whh1, bih1, bhh1,
        wih2, whh2, bih2, bhh2,
        fcw, fcb, (float*)d_out);
}